// Round 2
// 540.659 us; speedup vs baseline: 1.1990x; 1.1990x over previous
//
#include <hip/hip_runtime.h>

// out = swish(mw * swish(GN_{G=32}(x @ W^T + bias)))
// B=8192, K=4096, C=4096, fp32 I/O. fp32->bf16 cvt pre-pass into d_ws, then a
// 256x256x64 8-phase counted-vmcnt MFMA GEMM (T1+T2+T3+T4+T5 template) with
// block-local GroupNorm + swish epilogue. Group size 128; BN=256 = 2 groups.
// Round-2: resubmission of round-1 design (container infra failure, no verdict);
// added a one-time vmcnt(0)+barrier drain before the epilogue LDS overlay.

typedef short bf16x8 __attribute__((ext_vector_type(8)));
typedef unsigned short u16x8 __attribute__((ext_vector_type(8)));
typedef unsigned short u16x4 __attribute__((ext_vector_type(4)));
typedef float fx4 __attribute__((ext_vector_type(4)));

__device__ __forceinline__ unsigned short f2bf(float f) {
    union { float f; unsigned u; } v; v.f = f;
    unsigned r = v.u + 0x7FFFu + ((v.u >> 16) & 1u);   // RTNE
    return (unsigned short)(r >> 16);
}

__device__ __forceinline__ void load_lds16(const void* g, void* l) {
    __builtin_amdgcn_global_load_lds(
        (const __attribute__((address_space(1))) void*)g,
        (__attribute__((address_space(3))) void*)l, 16, 0, 0);
}

// ---------------- fused fp32 -> bf16 convert pre-pass (X then W) ----------------
__global__ void __launch_bounds__(256)
cvt_both(const float* __restrict__ X, const float* __restrict__ W,
         unsigned short* __restrict__ Xb, unsigned short* __restrict__ Wb,
         long long nX, long long nW) {
    long long i = ((long long)blockIdx.x * 256 + threadIdx.x) * 8;
    const float* src; unsigned short* dst; long long j;
    if (i < nX) { src = X; dst = Xb; j = i; }
    else { j = i - nX; if (j >= nW) return; src = W; dst = Wb; }
    float4 a = *(const float4*)(src + j);
    float4 b = *(const float4*)(src + j + 4);
    u16x8 o;
    o[0] = f2bf(a.x); o[1] = f2bf(a.y); o[2] = f2bf(a.z); o[3] = f2bf(a.w);
    o[4] = f2bf(b.x); o[5] = f2bf(b.y); o[6] = f2bf(b.z); o[7] = f2bf(b.w);
    *(u16x8*)(dst + j) = o;
}

// ---------------- 256x256 8-phase GEMM + fused epilogue ----------------
#define BAR()    do { __builtin_amdgcn_s_barrier(); asm volatile("" ::: "memory"); } while (0)
#define LGKM0()  asm volatile("s_waitcnt lgkmcnt(0)" ::: "memory")
#define VMCNT(n) asm volatile("s_waitcnt vmcnt(" #n ")" ::: "memory")

__global__ void __launch_bounds__(512, 2)
gemm256(const unsigned short* __restrict__ X,    // [8192,4096] bf16 (ws)
        const unsigned short* __restrict__ Wt,   // [4096,4096] bf16 (ws)
        const float* __restrict__ bias, const float* __restrict__ gnw,
        const float* __restrict__ gnb,  const float* __restrict__ mw,
        float* __restrict__ out)
{
    constexpr int Kd = 4096;
    constexpr int NT = 64;                      // K / BK, BK = 64
    // [buf][khalf][256 rows][32 cols] bf16, 16 KB per (buf,khalf) region.
    __shared__ __align__(16) unsigned short As[32768];   // 64 KB
    __shared__ __align__(16) unsigned short Bs[32768];   // 64 KB

    const int tid  = threadIdx.x;
    const int w    = tid >> 6;                  // 8 waves
    const int lane = tid & 63;
    const int wm = w >> 2, wn = w & 3;          // 2 x 4 wave grid, 128x64 each
    const int lrow = lane & 15, q = lane >> 4;

    // XCD-aware swizzle over 512 blocks (bijective, 512 % 8 == 0)
    const int bid = blockIdx.x;
    const int swz = (bid & 7) * 64 + (bid >> 3);
    const int n0 = (swz & 15) * 256;            // 16 n-tiles
    const int m0 = (swz >> 4) * 256;            // 32 m-tiles

    const unsigned short* Atile = X  + (size_t)m0 * Kd;
    const unsigned short* Btile = Wt + (size_t)n0 * Kd;

    // staging decode: wave w writes LDS bytes [w*1024 + lane*16] of each 8KB
    // half-region (rows w*16..w*16+15). LDS dest is linear; the XOR swizzle is
    // applied on the GLOBAL source (rule #21).
    const int srow0 = w * 16 + (lane >> 2);     // rows 0..127 (half 0)
    const int skc   = (lane & 3) ^ ((srow0 >> 1) & 3);
    const size_t soff0 = (size_t)srow0 * Kd + skc * 8;
    const size_t soff1 = soff0 + (size_t)128 * Kd;

    // frag-read swizzle: slot = kc ^ ((row>>1)&3); (row>>1)&3 == (lrow>>1)&3
    const int fsw  = q ^ ((lrow >> 1) & 3);
    const int aoff = (wm * 128 + lrow) * 32 + fsw * 8;
    const int boff = (wn * 64  + lrow) * 32 + fsw * 8;

    fx4 acc[8][4];
    const fx4 zero = {0.f, 0.f, 0.f, 0.f};
    #pragma unroll
    for (int i = 0; i < 8; i++)
        #pragma unroll
        for (int j = 0; j < 4; j++) acc[i][j] = zero;

    bf16x8 fa[4], fb[4];

#define STAGE(gt, reg) do { \
    load_lds16((gt) + soff0, (reg) + w * 512); \
    load_lds16((gt) + soff1, (reg) + 4096 + w * 512); \
} while (0)

#define LDA4(regbase, MH) do { \
    _Pragma("unroll") \
    for (int _i = 0; _i < 4; _i++) \
        fa[_i] = *(const bf16x8*)((regbase) + aoff + (MH) * 2048 + _i * 512); \
} while (0)

#define LDB4(regbase) do { \
    _Pragma("unroll") \
    for (int _j = 0; _j < 4; _j++) \
        fb[_j] = *(const bf16x8*)((regbase) + boff + _j * 512); \
} while (0)

#define MMA(MH) do { \
    __builtin_amdgcn_s_setprio(1); \
    _Pragma("unroll") \
    for (int _i = 0; _i < 4; _i++) \
        _Pragma("unroll") \
        for (int _j = 0; _j < 4; _j++) \
            acc[(MH)*4+_i][_j] = __builtin_amdgcn_mfma_f32_16x16x32_bf16( \
                fa[_i], fb[_j], acc[(MH)*4+_i][_j], 0, 0, 0); \
    __builtin_amdgcn_s_setprio(0); \
} while (0)

    // K-tile: 4 phases = (khalf, mh). Stages: p0->A-k1(kt+1), p1->B-k1(kt+1),
    // p2->A-k0(kt+2) (own-buffer k0, last read at p1 -> WAR-safe across the
    // p1 end-barrier), p3->B-k0(kt+2). One vmcnt(4) checkpoint per K-tile:
    // newest 2 stages (4 loads) may stay in flight.
#define KTILE(BUF, ktv) do { \
    unsigned short* A0  = As + (BUF) * 16384; \
    unsigned short* A1  = A0 + 8192; \
    unsigned short* B0  = Bs + (BUF) * 16384; \
    unsigned short* B1  = B0 + 8192; \
    unsigned short* nA1 = As + ((BUF) ^ 1) * 16384 + 8192; \
    unsigned short* nB1 = Bs + ((BUF) ^ 1) * 16384 + 8192; \
    int _j1 = (ktv) + 1; if (_j1 > NT - 1) _j1 = NT - 1; \
    int _j2 = (ktv) + 2; if (_j2 > NT - 1) _j2 = NT - 1; \
    /* p0: k0, mh0 */ \
    LDB4(B0); LDA4(A0, 0); \
    STAGE(Atile + _j1 * 64 + 32, nA1); \
    BAR(); LGKM0(); MMA(0); BAR(); \
    /* p1: k0, mh1 */ \
    LDA4(A0, 1); \
    STAGE(Btile + _j1 * 64 + 32, nB1); \
    BAR(); LGKM0(); MMA(1); BAR(); \
    /* p2: k1, mh0 */ \
    LDB4(B1); LDA4(A1, 0); \
    STAGE(Atile + _j2 * 64, A0); \
    BAR(); LGKM0(); MMA(0); BAR(); \
    /* p3: k1, mh1 + checkpoint */ \
    LDA4(A1, 1); \
    STAGE(Btile + _j2 * 64, B0); \
    BAR(); LGKM0(); MMA(1); \
    VMCNT(4); BAR(); \
} while (0)

    // prologue: kt0 fully + k0 of kt1; allow the 2 newest stages in flight
    STAGE(Atile + 0,  As + 0);        // A-k0(0)
    STAGE(Btile + 0,  Bs + 0);        // B-k0(0)
    STAGE(Atile + 32, As + 8192);     // A-k1(0)
    STAGE(Btile + 32, Bs + 8192);     // B-k1(0)
    STAGE(Atile + 64, As + 16384);    // A-k0(1)
    STAGE(Btile + 64, Bs + 16384);    // B-k0(1)
    VMCNT(4); BAR();

    #pragma unroll 1
    for (int kt = 0; kt < NT; kt += 2) {
        KTILE(0, kt);
        KTILE(1, kt + 1);
    }

    // drain all in-flight staging before overlaying reduction scratch on As
    VMCNT(0); BAR();

    // ---------------- epilogue: bias + GroupNorm(128) + swish*mw*swish ----------------
    float* redS = (float*)As;          // 1024 floats
    float* redQ = (float*)As + 1024;   // 1024 floats

    float bia[4], gwv[4], gbv[4], mwv[4]; int cdx[4];
    #pragma unroll
    for (int nt = 0; nt < 4; nt++) {
        int c = n0 + wn * 64 + nt * 16 + lrow;
        cdx[nt] = c;
        bia[nt] = bias[c]; gwv[nt] = gnw[c]; gbv[nt] = gnb[c]; mwv[nt] = mw[c];
    }
    #pragma unroll
    for (int mt = 0; mt < 8; mt++)
        #pragma unroll
        for (int nt = 0; nt < 4; nt++)
            #pragma unroll
            for (int r = 0; r < 4; r++)
                acc[mt][nt][r] += bia[nt];

    // per-wave partial sum/sumsq over its 64 cols -> LDS
    #pragma unroll
    for (int mt = 0; mt < 8; mt++) {
        float sv[4], qv[4];
        #pragma unroll
        for (int r = 0; r < 4; r++) {
            float a = 0.f, b = 0.f;
            #pragma unroll
            for (int nt = 0; nt < 4; nt++) { float v = acc[mt][nt][r]; a += v; b += v * v; }
            sv[r] = a; qv[r] = b;
        }
        #pragma unroll
        for (int off = 1; off < 16; off <<= 1)
            #pragma unroll
            for (int r = 0; r < 4; r++) {
                sv[r] += __shfl_xor(sv[r], off, 64);
                qv[r] += __shfl_xor(qv[r], off, 64);
            }
        if (lrow == 0) {
            #pragma unroll
            for (int r = 0; r < 4; r++) {
                redS[w * 128 + mt * 16 + q * 4 + r] = sv[r];
                redQ[w * 128 + mt * 16 + q * 4 + r] = qv[r];
            }
        }
    }
    __syncthreads();

    const int pw = w ^ 1;   // partner wave: wn 0<->1, 2<->3 (same 128-col group)
    #pragma unroll
    for (int mt = 0; mt < 8; mt++) {
        #pragma unroll
        for (int r = 0; r < 4; r++) {
            int ri = mt * 16 + q * 4 + r;
            float tot = redS[w * 128 + ri] + redS[pw * 128 + ri];
            float tq  = redQ[w * 128 + ri] + redQ[pw * 128 + ri];
            float mean = tot * (1.0f / 128.0f);
            float rstd = rsqrtf(tq * (1.0f / 128.0f) - mean * mean + 1e-5f);
            size_t row = (size_t)(m0 + wm * 128 + mt * 16 + q * 4 + r);
            float* orow = out + row * 4096;
            #pragma unroll
            for (int nt = 0; nt < 4; nt++) {
                float h  = acc[mt][nt][r];
                float hn = (h - mean) * rstd;
                hn = hn * gwv[nt] + gbv[nt];
                float x1 = hn / (1.0f + __expf(-hn));
                float x2 = x1 * mwv[nt];
                orow[cdx[nt]] = x2 / (1.0f + __expf(-x2));
            }
        }
    }
#undef STAGE
#undef LDA4
#undef LDB4
#undef MMA
#undef KTILE
}

// ---------------- fallback: fp32 inputs, 128^2 tile, convert during staging ----------------
__device__ __forceinline__ void
epilogue_f(fx4 (&acc)[4][4],
           const float* __restrict__ bias, const float* __restrict__ gnw,
           const float* __restrict__ gnb,  const float* __restrict__ mw,
           float* __restrict__ out, int m0, int n0,
           int wm, int wn, int lrow, int q,
           float (*redS)[128], float (*redQ)[128]) {
    constexpr int C = 4096;
    float bia[4], gw[4], gb[4], mwv[4];
    int cidx[4];
    #pragma unroll
    for (int nt = 0; nt < 4; nt++) {
        int c = n0 + wn * 64 + nt * 16 + lrow;
        cidx[nt] = c;
        bia[nt] = bias[c]; gw[nt] = gnw[c]; gb[nt] = gnb[c]; mwv[nt] = mw[c];
    }
    #pragma unroll
    for (int mt = 0; mt < 4; mt++)
        #pragma unroll
        for (int nt = 0; nt < 4; nt++)
            #pragma unroll
            for (int r = 0; r < 4; r++)
                acc[mt][nt][r] += bia[nt];

    float s[4][4], ss[4][4];
    #pragma unroll
    for (int mt = 0; mt < 4; mt++)
        #pragma unroll
        for (int r = 0; r < 4; r++) {
            float a = 0.f, b = 0.f;
            #pragma unroll
            for (int nt = 0; nt < 4; nt++) {
                float v = acc[mt][nt][r];
                a += v; b += v * v;
            }
            s[mt][r] = a; ss[mt][r] = b;
        }
    #pragma unroll
    for (int off = 1; off < 16; off <<= 1)
        #pragma unroll
        for (int mt = 0; mt < 4; mt++)
            #pragma unroll
            for (int r = 0; r < 4; r++) {
                s[mt][r]  += __shfl_xor(s[mt][r],  off, 64);
                ss[mt][r] += __shfl_xor(ss[mt][r], off, 64);
            }
    if (lrow == 0) {
        #pragma unroll
        for (int mt = 0; mt < 4; mt++)
            #pragma unroll
            for (int r = 0; r < 4; r++) {
                int row = wm * 64 + mt * 16 + q * 4 + r;
                redS[wn][row] = s[mt][r];
                redQ[wn][row] = ss[mt][r];
            }
    }
    __syncthreads();

    #pragma unroll
    for (int mt = 0; mt < 4; mt++)
        #pragma unroll
        for (int r = 0; r < 4; r++) {
            int row = wm * 64 + mt * 16 + q * 4 + r;
            float tot  = redS[0][row] + redS[1][row];
            float tq   = redQ[0][row] + redQ[1][row];
            float mean = tot * (1.0f / 128.0f);
            float var  = tq * (1.0f / 128.0f) - mean * mean;
            s[mt][r]  = mean;
            ss[mt][r] = rsqrtf(var + 1e-5f);
        }

    #pragma unroll
    for (int mt = 0; mt < 4; mt++)
        #pragma unroll
        for (int r = 0; r < 4; r++) {
            size_t row = (size_t)(m0 + wm * 64 + mt * 16 + q * 4 + r);
            #pragma unroll
            for (int nt = 0; nt < 4; nt++) {
                float h  = acc[mt][nt][r];
                float hn = (h - s[mt][r]) * ss[mt][r];
                hn = hn * gw[nt] + gb[nt];
                float x1 = hn / (1.0f + __expf(-hn));
                float x2 = x1 * mwv[nt];
                float y  = x2 / (1.0f + __expf(-x2));
                out[row * (size_t)C + cidx[nt]] = y;
            }
        }
}

__global__ void __launch_bounds__(256)
gemm_f32cvt(const float* __restrict__ X, const float* __restrict__ Wt,
            const float* __restrict__ bias, const float* __restrict__ gnw,
            const float* __restrict__ gnb,  const float* __restrict__ mw,
            float* __restrict__ out)
{
    constexpr int K = 4096;
    __shared__ __align__(16) unsigned short As[128 * 32];
    __shared__ __align__(16) unsigned short Bs[128 * 32];
    __shared__ float redS[2][128];
    __shared__ float redQ[2][128];

    const int tid  = threadIdx.x;
    const int wave = tid >> 6;
    const int lane = tid & 63;
    const int wm = wave >> 1, wn = wave & 1;
    const int lrow = lane & 15;
    const int q    = lane >> 4;

    const int m0 = blockIdx.y * 128;
    const int n0 = blockIdx.x * 128;

    const int srow = tid >> 3;
    const int sk   = (tid & 7) * 4;

    fx4 acc[4][4];
    const fx4 zero = {0.f, 0.f, 0.f, 0.f};
    #pragma unroll
    for (int i = 0; i < 4; i++)
        #pragma unroll
        for (int j = 0; j < 4; j++) acc[i][j] = zero;

    for (int k0 = 0; k0 < K; k0 += 32) {
        #pragma unroll
        for (int j = 0; j < 4; j++) {
            int row = j * 32 + srow;
            float4 va = *(const float4*)(X  + (size_t)(m0 + row) * K + k0 + sk);
            float4 vb = *(const float4*)(Wt + (size_t)(n0 + row) * K + k0 + sk);
            u16x4 oa = { f2bf(va.x), f2bf(va.y), f2bf(va.z), f2bf(va.w) };
            u16x4 ob = { f2bf(vb.x), f2bf(vb.y), f2bf(vb.z), f2bf(vb.w) };
            *(u16x4*)&As[row * 32 + sk] = oa;
            *(u16x4*)&Bs[row * 32 + sk] = ob;
        }
        __syncthreads();

        bf16x8 af[4], bfr[4];
        #pragma unroll
        for (int mt = 0; mt < 4; mt++)
            af[mt] = *(const bf16x8*)&As[(wm * 64 + mt * 16 + lrow) * 32 + q * 8];
        #pragma unroll
        for (int nt = 0; nt < 4; nt++)
            bfr[nt] = *(const bf16x8*)&Bs[(wn * 64 + nt * 16 + lrow) * 32 + q * 8];

        #pragma unroll
        for (int mt = 0; mt < 4; mt++)
            #pragma unroll
            for (int nt = 0; nt < 4; nt++)
                acc[mt][nt] = __builtin_amdgcn_mfma_f32_16x16x32_bf16(
                    af[mt], bfr[nt], acc[mt][nt], 0, 0, 0);
        __syncthreads();
    }

    epilogue_f(acc, bias, gnw, gnb, mw, out, m0, n0, wm, wn, lrow, q, redS, redQ);
}

extern "C" void kernel_launch(void* const* d_in, const int* in_sizes, int n_in,
                              void* d_out, int out_size, void* d_ws, size_t ws_size,
                              hipStream_t stream) {
    (void)in_sizes; (void)n_in; (void)out_size;
    const float* X    = (const float*)d_in[0];   // [8192,4096]
    const float* Wt   = (const float*)d_in[1];   // [4096,4096]
    const float* bias = (const float*)d_in[2];
    const float* gnw  = (const float*)d_in[3];
    const float* gnb  = (const float*)d_in[4];
    const float* mw   = (const float*)d_in[5];
    float* out = (float*)d_out;

    const long long nX = 8192LL * 4096LL;
    const long long nW = 4096LL * 4096LL;
    const size_t need = (size_t)(nX + nW) * 2;

    if (ws_size >= need) {
        unsigned short* Xb = (unsigned short*)d_ws;
        unsigned short* Wb = Xb + nX;
        cvt_both<<<(int)((nX + nW) / 8 / 256), 256, 0, stream>>>(X, Wt, Xb, Wb, nX, nW);
        gemm256<<<512, 512, 0, stream>>>(Xb, Wb, bias, gnw, gnb, mw, out);
    } else {
        dim3 grid(4096 / 128, 8192 / 128);
        gemm_f32cvt<<<grid, 256, 0, stream>>>(X, Wt, bias, gnw, gnb, mw, out);
    }
}